// Round 1
// baseline (178.924 us; speedup 1.0000x reference)
//
#include <hip/hip_runtime.h>
#include <math.h>

#define TW   32
#define TH   32
#define HALO 5
#define EXT  42          // TH + 2*HALO
#define SXW  44          // padded LDS row stride for raw tiles
#define IMG  512
#define NIMG 48          // B*C = 16*3
#define NPIX 12582912.0  // 48*512*512

// Normalized 11-tap Gaussian, sigma=1.5 (matches np.exp(-ax^2/4.5)/sum)
__constant__ float G11[11] = {
    0.00102838f, 0.00759876f, 0.03600077f, 0.10936069f, 0.21300554f,
    0.26601173f,
    0.21300554f, 0.10936069f, 0.03600077f, 0.00759876f, 0.00102838f
};

__global__ __launch_bounds__(256) void ssim_tile_kernel(
    const float* __restrict__ x, const float* __restrict__ y,
    double* __restrict__ acc)
{
    __shared__ float sx[EXT][SXW];
    __shared__ float sy[EXT][SXW];
    __shared__ float hb[5][EXT][TW + 1];
    __shared__ float wsum[4];

    const int tid = threadIdx.x;
    const int c0  = blockIdx.x * TW;
    const int r0  = blockIdx.y * TH;
    const int img = blockIdx.z;
    const float* __restrict__ xb = x + (size_t)img * IMG * IMG;
    const float* __restrict__ yb = y + (size_t)img * IMG * IMG;

    // ---- stage 42x42 halo tile (zero padding outside image) ----
    for (int i = tid; i < EXT * EXT; i += 256) {
        int rr = i / EXT;
        int cc = i - rr * EXT;
        int gr = r0 - HALO + rr;
        int gc = c0 - HALO + cc;
        float vx = 0.f, vy = 0.f;
        if (gr >= 0 && gr < IMG && gc >= 0 && gc < IMG) {
            int gi = gr * IMG + gc;
            vx = xb[gi];
            vy = yb[gi];
        }
        sx[rr][cc] = vx;
        sy[rr][cc] = vy;
    }
    __syncthreads();

    // ---- horizontal 11-tap pass over 42 rows x 32 cols ----
    for (int i = tid; i < EXT * TW; i += 256) {
        int rr = i >> 5;
        int cc = i & 31;
        float ax = 0.f, ay = 0.f, axx = 0.f, ayy = 0.f, axy = 0.f;
#pragma unroll
        for (int k = 0; k < 11; ++k) {
            float g  = G11[k];
            float vx = sx[rr][cc + k];
            float vy = sy[rr][cc + k];
            ax  += g * vx;
            ay  += g * vy;
            axx += g * vx * vx;
            ayy += g * vy * vy;
            axy += g * vx * vy;
        }
        hb[0][rr][cc] = ax;
        hb[1][rr][cc] = ay;
        hb[2][rr][cc] = axx;
        hb[3][rr][cc] = ayy;
        hb[4][rr][cc] = axy;
    }
    __syncthreads();

    // ---- vertical 11-tap pass + pointwise SSIM + local sum ----
    float lsum = 0.f;
    for (int i = tid; i < TH * TW; i += 256) {
        int rr = i >> 5;
        int cc = i & 31;
        float mx = 0.f, my = 0.f, mxx = 0.f, myy = 0.f, mxy = 0.f;
#pragma unroll
        for (int k = 0; k < 11; ++k) {
            float g = G11[k];
            mx  += g * hb[0][rr + k][cc];
            my  += g * hb[1][rr + k][cc];
            mxx += g * hb[2][rr + k][cc];
            myy += g * hb[3][rr + k][cc];
            mxy += g * hb[4][rr + k][cc];
        }
        float mx2  = mx * mx;
        float my2  = my * my;
        float varx = mxx - mx2;
        float vary = myy - my2;
        float cov  = mxy - mx * my;
        float num  = (2.f * mx * my + 0.0001f) * (2.f * cov + 0.0009f);
        float den  = (mx2 + my2 + 0.0001f) * (varx + vary + 0.0009f);
        lsum += num / den;
    }

    // ---- block reduction: wave shuffle + LDS across 4 waves ----
#pragma unroll
    for (int off = 32; off > 0; off >>= 1)
        lsum += __shfl_down(lsum, off, 64);
    int wid  = tid >> 6;
    int lane = tid & 63;
    if (lane == 0) wsum[wid] = lsum;
    __syncthreads();
    if (tid == 0) {
        float s = wsum[0] + wsum[1] + wsum[2] + wsum[3];
        atomicAdd(acc, (double)s);
    }
}

__global__ void ssim_finalize_kernel(const double* __restrict__ acc,
                                     float* __restrict__ out)
{
    double mean = acc[0] / NPIX;
    out[0] = (float)(-log10(mean));  // loss
    out[1] = (float)mean;            // ssim_mean
}

extern "C" void kernel_launch(void* const* d_in, const int* in_sizes, int n_in,
                              void* d_out, int out_size, void* d_ws, size_t ws_size,
                              hipStream_t stream)
{
    const float* x = (const float*)d_in[0];
    const float* y = (const float*)d_in[1];
    float* out     = (float*)d_out;
    double* acc    = (double*)d_ws;

    hipMemsetAsync(acc, 0, sizeof(double), stream);

    dim3 grid(IMG / TW, IMG / TH, NIMG);
    ssim_tile_kernel<<<grid, 256, 0, stream>>>(x, y, acc);
    ssim_finalize_kernel<<<1, 1, 0, stream>>>(acc, out);
}